// Round 13
// baseline (2147.704 us; speedup 1.0000x reference)
//
#include <hip/hip_runtime.h>

#define SEQ 512
#define T3 1536
#define CDIM 768
#define NH 12
#define HD 64
#define NL 6

typedef __attribute__((ext_vector_type(8))) short bh8;
typedef __attribute__((ext_vector_type(4))) short s4;
typedef __attribute__((ext_vector_type(4))) float f4;

__device__ inline short f2bf(float f) {
    union { float f; unsigned u; } x; x.f = f;
    unsigned r = x.u + 0x7FFFu + ((x.u >> 16) & 1u);
    return (short)(r >> 16);
}

__device__ inline float bf2f(short s) {
    union { unsigned u; float f; } x;
    x.u = ((unsigned)(unsigned short)s) << 16;
    return x.f;
}

__device__ inline void gload16(const short* g, const short* l) {
    __builtin_amdgcn_global_load_lds(
        (const __attribute__((address_space(1))) unsigned int*)g,
        (__attribute__((address_space(3))) unsigned int*)l, 16, 0, 0);
}

__device__ inline float block_sum(float v, volatile float* red, int tid) {
    #pragma unroll
    for (int off = 32; off > 0; off >>= 1) v += __shfl_down(v, off, 64);
    __syncthreads();
    if ((tid & 63) == 0) red[tid >> 6] = v;
    __syncthreads();
    return red[0] + red[1] + red[2] + red[3];
}

// ---------------- weight transpose + bf16 conversion (r8 best: 71us) -------
__global__ __launch_bounds__(256) void conv64_k(
        const float* __restrict__ Wq, const float* __restrict__ Wk,
        const float* __restrict__ Wv, const float* __restrict__ Wp,
        const float* __restrict__ W1, const float* __restrict__ W2,
        short* __restrict__ dst, int l0) {
    __shared__ float t2[2][64][65];      // [tile][n][k]
    int tid = threadIdx.x;
    int rk = tid >> 4, cn4 = (tid & 15) * 4;
    const float* srcA[2]; short* dA[2]; int KA[2], k0A[2], n0A[2];
    f4 vv[2][4];
    #pragma unroll
    for (int i = 0; i < 2; ++i) {
        int tt = blockIdx.x * 2 + i;
        int lrel = tt / 1728, r = tt - lrel * 1728;
        int l = l0 + lrel;
        short* dstL = dst + (size_t)lrel * 7077888;
        const float* src; short* d; int K, N, tk, tn;
        if (r < 576) {
            int mat = r / 144, t = r - mat * 144;
            tk = t / 12; tn = t % 12; K = 768; N = 768;
            const float* srcs[4] = {Wq, Wk, Wv, Wp};
            src = srcs[mat] + (size_t)l * 589824;
            d = dstL + mat * 589824;
        } else if (r < 1152) {
            int t = r - 576; tk = t / 48; tn = t % 48; K = 768; N = 3072;
            src = W1 + (size_t)l * 2359296; d = dstL + 2359296;
        } else {
            int t = r - 1152; tk = t / 12; tn = t % 12; K = 3072; N = 768;
            src = W2 + (size_t)l * 2359296; d = dstL + 4718592;
        }
        int k0 = tk * 64, n0 = tn * 64;
        srcA[i] = src; dA[i] = d; KA[i] = K; k0A[i] = k0; n0A[i] = n0;
        #pragma unroll
        for (int p = 0; p < 4; ++p)
            vv[i][p] = *(const f4*)(src + (size_t)(k0 + p * 16 + rk) * N + n0 + cn4);
    }
    #pragma unroll
    for (int i = 0; i < 2; ++i)
    #pragma unroll
    for (int p = 0; p < 4; ++p) {
        t2[i][cn4][p * 16 + rk]     = vv[i][p][0];
        t2[i][cn4 + 1][p * 16 + rk] = vv[i][p][1];
        t2[i][cn4 + 2][p * 16 + rk] = vv[i][p][2];
        t2[i][cn4 + 3][p * 16 + rk] = vv[i][p][3];
    }
    __syncthreads();
    int n = tid >> 2, kb = (tid & 3) * 16;
    #pragma unroll
    for (int i = 0; i < 2; ++i) {
        f4 a0 = *(const f4*)&t2[i][n][kb];
        f4 a1 = *(const f4*)&t2[i][n][kb + 4];
        f4 a2 = *(const f4*)&t2[i][n][kb + 8];
        f4 a3 = *(const f4*)&t2[i][n][kb + 12];
        bh8 o0, o1;
        o0[0] = f2bf(a0[0]); o0[1] = f2bf(a0[1]); o0[2] = f2bf(a0[2]); o0[3] = f2bf(a0[3]);
        o0[4] = f2bf(a1[0]); o0[5] = f2bf(a1[1]); o0[6] = f2bf(a1[2]); o0[7] = f2bf(a1[3]);
        o1[0] = f2bf(a2[0]); o1[1] = f2bf(a2[1]); o1[2] = f2bf(a2[2]); o1[3] = f2bf(a2[3]);
        o1[4] = f2bf(a3[0]); o1[5] = f2bf(a3[1]); o1[6] = f2bf(a3[2]); o1[7] = f2bf(a3[3]);
        short* wp = dA[i] + (size_t)(n0A[i] + n) * KA[i] + k0A[i] + kb;
        *(bh8*)wp = o0;
        *(bh8*)(wp + 8) = o1;
    }
}

// ---------------- embedding + LN0 ----------------
__global__ __launch_bounds__(256) void embed_ln0_k(
        const float* __restrict__ states, const float* __restrict__ actions,
        const float* __restrict__ goals, const int* __restrict__ timesteps,
        const float* __restrict__ W_s, const float* __restrict__ b_s,
        const float* __restrict__ W_a, const float* __restrict__ b_a,
        const float* __restrict__ W_g, const float* __restrict__ b_g,
        const float* __restrict__ E_t, const float* __restrict__ g0,
        const float* __restrict__ bb0, float* __restrict__ x, short* __restrict__ xb) {
    int row = blockIdx.x;
    int b = row / T3, t3 = row - b * T3;
    int t = t3 / 3, kind = t3 - t * 3;
    __shared__ float inv[64];
    __shared__ float xr[CDIM];
    __shared__ float red[4];
    int tid = threadIdx.x;
    const float* src; const float* W; const float* bias;
    if (kind == 0)      { src = goals + b * 64;                       W = W_g; bias = b_g; }
    else if (kind == 1) { src = states + ((size_t)b * SEQ + t) * 64;  W = W_s; bias = b_s; }
    else                { src = actions + ((size_t)b * SEQ + t) * 64; W = W_a; bias = b_a; }
    if (tid < 64) inv[tid] = src[tid];
    __syncthreads();
    int ts = timesteps[b * SEQ + t];
    for (int c = tid; c < CDIM; c += 256) {
        float acc = bias[c] + E_t[(size_t)ts * CDIM + c];
        #pragma unroll 8
        for (int kk = 0; kk < 64; ++kk) acc += inv[kk] * W[kk * CDIM + c];
        xr[c] = acc;
    }
    __syncthreads();
    float v0 = xr[tid], v1 = xr[tid + 256], v2 = xr[tid + 512];
    float mean = block_sum(v0 + v1 + v2, red, tid) * (1.f / CDIM);
    float d0 = v0 - mean, d1 = v1 - mean, d2 = v2 - mean;
    float var = block_sum(d0 * d0 + d1 * d1 + d2 * d2, red, tid) * (1.f / CDIM);
    float rs = rsqrtf(var + 1e-5f);
    float* w = x + (size_t)row * CDIM;
    short* wb = xb + (size_t)row * CDIM;
    float o0 = d0 * rs * g0[tid]       + bb0[tid];
    float o1 = d1 * rs * g0[tid + 256] + bb0[tid + 256];
    float o2 = d2 * rs * g0[tid + 512] + bb0[tid + 512];
    w[tid] = o0; w[tid + 256] = o1; w[tid + 512] = o2;
    wb[tid] = f2bf(o0); wb[tid + 256] = f2bf(o1); wb[tid + 512] = f2bf(o2);
}

// ------- standalone LayerNorm (fallback path only) ------
__global__ __launch_bounds__(256) void ln_k(float* __restrict__ x, short* __restrict__ outb,
                                            const float* __restrict__ g, const float* __restrict__ bb) {
    int wave = threadIdx.x >> 6, lane = threadIdx.x & 63;
    int row = blockIdx.x * 4 + wave;
    float* r = x + (size_t)row * CDIM;
    short* wb = outb + (size_t)row * CDIM;
    float v[12];
    float s = 0.f, s2 = 0.f;
    #pragma unroll
    for (int j = 0; j < 12; ++j) {
        v[j] = r[lane + j * 64];
        s += v[j]; s2 += v[j] * v[j];
    }
    #pragma unroll
    for (int off = 32; off > 0; off >>= 1) { s += __shfl_xor(s, off, 64); s2 += __shfl_xor(s2, off, 64); }
    float mean = s * (1.f / CDIM);
    float var = s2 * (1.f / CDIM) - mean * mean;
    float rs = rsqrtf(var + 1e-5f);
    #pragma unroll
    for (int j = 0; j < 12; ++j) {
        int c = lane + j * 64;
        float o = (v[j] - mean) * rs * g[c] + bb[c];
        r[c] = o;
        wb[c] = f2bf(o);
    }
}

// ----- BMxBN MFMA GEMM, BK=64, swizzled LDS, gload staging -----------------
// DB=1: double-buffered LDS + counted vmcnt(4) + raw barriers.
// EPI 0: QKV scatter (z: 0=Q,1=K,2=V^T); EPI 1: outF += acc+bias (residual);
// EPI 2: outQ = bf16(gelu(acc+bias)).
// FLN=1 (EPI1 only): fused LayerNorm via atomic row-panel counter; the last
// column-block per row panel normalizes its 64 rows (x_f in-place + bf16 out).
// cntZ: counter array zeroed at entry (used by EPI2 to prep the next gemm).
template<int BM, int BN, int EPI, int DB, int FLN>
__global__ __launch_bounds__(256) void gemm6_k(
        const short* __restrict__ A, const short* __restrict__ B0,
        const short* __restrict__ B1, const short* __restrict__ B2,
        const float* __restrict__ bias0, const float* __restrict__ bias1,
        const float* __restrict__ bias2,
        float* __restrict__ outF, short* __restrict__ outQ,
        short* __restrict__ outK, short* __restrict__ outV,
        int N, int K,
        const float* __restrict__ lnG, const float* __restrict__ lnB,
        short* __restrict__ lnOut, int* cnt, int* cntZ) {
    if (EPI == 2 && cntZ != nullptr && blockIdx.x == 0 && blockIdx.y == 0 && threadIdx.x < 48)
        cntZ[threadIdx.x] = 0;
    const short* Bw = B0; const float* bias = bias0; short* outB = outQ;
    int zid = 0;
    if (EPI == 0) {
        zid = blockIdx.z;
        if (zid == 1) { Bw = B1; bias = bias1; outB = outK; }
        else if (zid == 2) { Bw = B2; bias = bias2; outB = outV; }
    }
    __shared__ short As[(DB ? 2 : 1) * BM * 64];
    __shared__ short Bs[(DB ? 2 : 1) * BN * 64];
    int tid = threadIdx.x, lane = tid & 63, wave = tid >> 6;
    int wm = wave >> 1, wn = wave & 1, lr = lane & 15, lg = lane >> 4;
    int bm = blockIdx.y * BM, bn = blockIdx.x * BN;
    int rl = lane >> 3, ch = (lane & 7) ^ rl;
    constexpr int MI = BM / 32, NI = BN / 32;
    f4 acc[MI][NI] = {};

    auto STAGE = [&](int k0, int buf) {
        #pragma unroll
        for (int j = 0; j < BM / 32; ++j)
            gload16(A + (size_t)(bm + wave * (BM / 4) + j * 8 + rl) * K + k0 + ch * 8,
                    As + buf * BM * 64 + (wave * (BM / 4) + j * 8) * 64);
        #pragma unroll
        for (int j = 0; j < BN / 32; ++j)
            gload16(Bw + (size_t)(bn + wave * (BN / 4) + j * 8 + rl) * K + k0 + ch * 8,
                    Bs + buf * BN * 64 + (wave * (BN / 4) + j * 8) * 64);
    };

    auto COMPUTE = [&](int buf) {
        bh8 af[MI][2], bf[NI][2];
        #pragma unroll
        for (int mi = 0; mi < MI; ++mi)
        #pragma unroll
        for (int kk = 0; kk < 2; ++kk) {
            int m = wm * (BM / 2) + mi * 16 + lr;
            af[mi][kk] = *(const bh8*)(As + buf * BM * 64 + m * 64 + (((kk * 4 + lg) ^ (lr & 7)) * 8));
        }
        #pragma unroll
        for (int ni = 0; ni < NI; ++ni)
        #pragma unroll
        for (int kk = 0; kk < 2; ++kk) {
            int n = wn * (BN / 2) + ni * 16 + lr;
            bf[ni][kk] = *(const bh8*)(Bs + buf * BN * 64 + n * 64 + (((kk * 4 + lg) ^ (lr & 7)) * 8));
        }
        #pragma unroll
        for (int kk = 0; kk < 2; ++kk)
        #pragma unroll
        for (int mi = 0; mi < MI; ++mi)
        #pragma unroll
        for (int ni = 0; ni < NI; ++ni)
            acc[mi][ni] = __builtin_amdgcn_mfma_f32_16x16x32_bf16(af[mi][kk], bf[ni][kk], acc[mi][ni], 0, 0, 0);
    };

    if (DB) {
        STAGE(0, 0);
        int cur = 0;
        for (int k0 = 0; k0 < K; k0 += 64) {
            if (k0 + 64 < K) {
                STAGE(k0 + 64, cur ^ 1);
                asm volatile("s_waitcnt vmcnt(4)" ::: "memory");
            } else {
                asm volatile("s_waitcnt vmcnt(0)" ::: "memory");
            }
            __builtin_amdgcn_s_barrier();
            __builtin_amdgcn_sched_barrier(0);
            COMPUTE(cur);
            __builtin_amdgcn_sched_barrier(0);
            __builtin_amdgcn_s_barrier();
            cur ^= 1;
        }
    } else {
        for (int k0 = 0; k0 < K; k0 += 64) {
            STAGE(k0, 0);
            __syncthreads();
            COMPUTE(0);
            __syncthreads();
        }
    }

    #pragma unroll
    for (int mi = 0; mi < MI; ++mi)
    #pragma unroll
    for (int ni = 0; ni < NI; ++ni)
    #pragma unroll
    for (int i = 0; i < 4; ++i) {
        int row = bm + wm * (BM / 2) + mi * 16 + lg * 4 + i;
        int col = bn + wn * (BN / 2) + ni * 16 + lr;
        float vv = acc[mi][ni][i] + bias[col];
        if (EPI == 0) {
            int b = row / T3, t = row - b * T3;
            int h = col >> 6, d = col & 63;
            if (zid == 2) outB[((size_t)(b * NH + h) * 64 + d) * T3 + t] = f2bf(vv);
            else          outB[((((size_t)b * NH + h) * T3 + t) << 6) + d] = f2bf(vv);
        } else if (EPI == 1) {
            size_t idx = (size_t)row * N + col;
            outF[idx] = vv + outF[idx];
        } else {
            float gl = 0.5f * vv * (1.0f + erff(vv * 0.70710678118f));
            outQ[(size_t)row * N + col] = f2bf(gl);
        }
    }

    if (FLN) {
        __threadfence();                       // release this block's stores
        __syncthreads();
        __shared__ int lastF;
        if (tid == 0) {
            int old = atomicAdd(&cnt[blockIdx.y], 1);
            lastF = (old == (int)gridDim.x - 1) ? 1 : 0;
        }
        __syncthreads();
        if (lastF) {
            __threadfence();                   // acquire all panels' stores
            int wv2 = tid >> 6, l2 = tid & 63;
            for (int rr = wv2; rr < BM; rr += 4) {
                int row = blockIdx.y * BM + rr;
                float* rp = outF + (size_t)row * CDIM;
                short* wp2 = lnOut + (size_t)row * CDIM;
                float vv2[12];
                float s = 0.f, s2 = 0.f;
                #pragma unroll
                for (int j = 0; j < 12; ++j) {
                    vv2[j] = rp[l2 + j * 64];
                    s += vv2[j]; s2 += vv2[j] * vv2[j];
                }
                #pragma unroll
                for (int off = 32; off > 0; off >>= 1) {
                    s += __shfl_xor(s, off, 64); s2 += __shfl_xor(s2, off, 64);
                }
                float mean = s * (1.f / CDIM);
                float var = s2 * (1.f / CDIM) - mean * mean;
                float rs = rsqrtf(var + 1e-5f);
                #pragma unroll
                for (int j = 0; j < 12; ++j) {
                    int c = l2 + j * 64;
                    float oo = (vv2[j] - mean) * rs * lnG[c] + lnB[c];
                    rp[c] = oo;
                    wp2[c] = f2bf(oo);
                }
            }
        }
    }
}

// ---------------- causal flash attention (no-max softmax, dbuf gload) -------
__global__ __launch_bounds__(256) void attn_k(const short* __restrict__ q, const short* __restrict__ k,
                                              const short* __restrict__ vt, short* __restrict__ att,
                                              int* cntZ) {
    int idx = blockIdx.x;
    if (cntZ != nullptr && idx == 0 && threadIdx.x < 48) cntZ[threadIdx.x] = 0;
    int qt = 23 - (idx / 24);          // heavy-first ordering
    int bh = idx % 24;
    int b = bh / NH, h = bh - b * NH;
    const short* qb = q  + (size_t)bh * T3 * HD;
    const short* kb = k  + (size_t)bh * T3 * HD;
    const short* vb = vt + (size_t)bh * HD * T3;
    __shared__ short Ks[2][4096];
    __shared__ short Vs[2][4096];
    __shared__ short Pl[4][16][72];
    int tid = threadIdx.x, lane = tid & 63, wave = tid >> 6;
    int lr = lane & 15, lg = lane >> 4;
    int rl = lane >> 3, ch = (lane & 7) ^ rl;
    int qrow0 = qt * 64 + wave * 16;
    bh8 aq0 = *(const bh8*)(qb + (size_t)(qrow0 + lr) * HD + lg * 8);
    bh8 aq1 = *(const bh8*)(qb + (size_t)(qrow0 + lr) * HD + 32 + lg * 8);
    f4 o[4] = {};
    float lsum[4] = {0.f, 0.f, 0.f, 0.f};

    auto STAGE = [&](int kt2, int buf) {
        const short* kb2 = kb + (size_t)kt2 * 64 * HD;
        #pragma unroll
        for (int j = 0; j < 2; ++j)
            gload16(kb2 + (wave * 16 + j * 8 + rl) * HD + ch * 8,
                    &Ks[buf][(wave * 16 + j * 8) * 64]);
        const short* vb2 = vb + kt2 * 64;
        #pragma unroll
        for (int j = 0; j < 2; ++j)
            gload16(vb2 + (size_t)(wave * 16 + j * 8 + rl) * T3 + ch * 8,
                    &Vs[buf][(wave * 16 + j * 8) * 64]);
    };

    STAGE(0, 0);
    int cur = 0;
    for (int kt = 0; kt <= qt; ++kt) {
        if (kt < qt) {
            STAGE(kt + 1, cur ^ 1);
            asm volatile("s_waitcnt vmcnt(4)" ::: "memory");
        } else {
            asm volatile("s_waitcnt vmcnt(0)" ::: "memory");
        }
        __builtin_amdgcn_s_barrier();
        __builtin_amdgcn_sched_barrier(0);
        const short* Kb = &Ks[cur][0];
        const short* Vb = &Vs[cur][0];
        f4 s[4];
        #pragma unroll
        for (int nf = 0; nf < 4; ++nf) {
            int tok = nf * 16 + lr;
            bh8 bk0 = *(const bh8*)(Kb + tok * 64 + ((lg ^ (lr & 7)) * 8));
            bh8 bk1 = *(const bh8*)(Kb + tok * 64 + (((4 + lg) ^ (lr & 7)) * 8));
            f4 t = {};
            t = __builtin_amdgcn_mfma_f32_16x16x32_bf16(aq0, bk0, t, 0, 0, 0);
            t = __builtin_amdgcn_mfma_f32_16x16x32_bf16(aq1, bk1, t, 0, 0, 0);
            s[nf] = t;
        }
        #pragma unroll
        for (int nf = 0; nf < 4; ++nf)
        #pragma unroll
        for (int i = 0; i < 4; ++i) {
            float p = __expf(s[nf][i] * 0.125f);
            if (kt == qt && (nf * 16 + lr) > (wave * 16 + lg * 4 + i)) p = 0.f;
            lsum[i] += p;
            Pl[wave][lg * 4 + i][nf * 16 + lr] = f2bf(p);
        }
        bh8 ap0 = *(const bh8*)&Pl[wave][lr][lg * 8];
        bh8 ap1 = *(const bh8*)&Pl[wave][lr][32 + lg * 8];
        #pragma unroll
        for (int nf = 0; nf < 4; ++nf) {
            int d = nf * 16 + lr;
            bh8 bv0 = *(const bh8*)(Vb + d * 64 + ((lg ^ (lr & 7)) * 8));
            bh8 bv1 = *(const bh8*)(Vb + d * 64 + (((4 + lg) ^ (lr & 7)) * 8));
            o[nf] = __builtin_amdgcn_mfma_f32_16x16x32_bf16(ap0, bv0, o[nf], 0, 0, 0);
            o[nf] = __builtin_amdgcn_mfma_f32_16x16x32_bf16(ap1, bv1, o[nf], 0, 0, 0);
        }
        __builtin_amdgcn_sched_barrier(0);
        __builtin_amdgcn_s_barrier();
        cur ^= 1;
    }
    float linv[4];
    #pragma unroll
    for (int i = 0; i < 4; ++i) {
        float l = lsum[i];
        #pragma unroll
        for (int off = 1; off < 16; off <<= 1) l += __shfl_xor(l, off, 16);
        linv[i] = 1.f / l;
    }
    #pragma unroll
    for (int nf = 0; nf < 4; ++nf)
    #pragma unroll
    for (int i = 0; i < 4; ++i) {
        int qrow = qrow0 + lg * 4 + i;
        att[((size_t)b * T3 + qrow) * CDIM + h * 64 + nf * 16 + lr] = f2bf(o[nf][i] * linv[i]);
    }
}

// ---------------- output heads (bf16 activations) ----------------
__global__ __launch_bounds__(64) void head_k(const short* __restrict__ x,
                                             const float* __restrict__ Wps, const float* __restrict__ bps,
                                             const float* __restrict__ Wpa, const float* __restrict__ bpa,
                                             float* __restrict__ out) {
    int o = blockIdx.y;
    int bs = blockIdx.x;
    int b = bs >> 9, t = bs & 511;
    int kind = (o == 0) ? 2 : 1;
    const float* W = (o == 0) ? Wps : Wpa;
    const float* bi = (o == 0) ? bps : bpa;
    const short* xr = x + ((size_t)b * T3 + t * 3 + kind) * CDIM;
    int n = threadIdx.x;
    float a0 = 0.f, a1 = 0.f, a2 = 0.f, a3 = 0.f;
    for (int kk = 0; kk < CDIM; kk += 4) {
        s4 xv = *(const s4*)(xr + kk);
        a0 = fmaf(bf2f(xv[0]), W[(kk)     * 64 + n], a0);
        a1 = fmaf(bf2f(xv[1]), W[(kk + 1) * 64 + n], a1);
        a2 = fmaf(bf2f(xv[2]), W[(kk + 2) * 64 + n], a2);
        a3 = fmaf(bf2f(xv[3]), W[(kk + 3) * 64 + n], a3);
    }
    float acc = bi[n] + ((a0 + a1) + (a2 + a3));
    if (o == 1) acc = tanhf(acc);
    out[(((size_t)o * 2 + b) * SEQ + t) * 64 + n] = acc;
}

extern "C" void kernel_launch(void* const* d_in, const int* in_sizes, int n_in,
                              void* d_out, int out_size, void* d_ws, size_t ws_size,
                              hipStream_t stream) {
    const float* states    = (const float*)d_in[0];
    const float* actions   = (const float*)d_in[1];
    const float* goals     = (const float*)d_in[2];
    const int*   timesteps = (const int*)d_in[4];
    const float* W_s = (const float*)d_in[5];  const float* b_s = (const float*)d_in[6];
    const float* W_a = (const float*)d_in[7];  const float* b_a = (const float*)d_in[8];
    const float* W_g = (const float*)d_in[9];  const float* b_g = (const float*)d_in[10];
    const float* E_t = (const float*)d_in[11];
    const float* ln0_g = (const float*)d_in[12]; const float* ln0_b = (const float*)d_in[13];
    const float* Wq = (const float*)d_in[14]; const float* bq = (const float*)d_in[15];
    const float* Wk = (const float*)d_in[16]; const float* bk = (const float*)d_in[17];
    const float* Wv = (const float*)d_in[18]; const float* bv = (const float*)d_in[19];
    const float* Wp = (const float*)d_in[20]; const float* bp = (const float*)d_in[21];
    const float* ln1_g = (const float*)d_in[22]; const float* ln1_b = (const float*)d_in[23];
    const float* W1 = (const float*)d_in[24]; const float* b1 = (const float*)d_in[25];
    const float* W2 = (const float*)d_in[26]; const float* b2 = (const float*)d_in[27];
    const float* ln2_g = (const float*)d_in[28]; const float* ln2_b = (const float*)d_in[29];
    const float* W_ps = (const float*)d_in[30]; const float* b_ps = (const float*)d_in[31];
    const float* W_pa = (const float*)d_in[32]; const float* b_pa = (const float*)d_in[33];

    char* ws = (char*)d_ws;
    float* x_f   = (float*)(ws);                    //  9.44 MB [3072][768] f32 residual
    short* x_bf  = (short*)(ws + 9437184);          //  4.72 MB [3072][768] bf16
    // U region (18.87 MB): h_bf  OR  (qb,kb,vbt) -- never live simultaneously
    short* h_bf  = (short*)(ws + 14155776);         // 18.87 MB [3072][3072] bf16
    short* qb    = (short*)(ws + 14155776);
    short* kb    = (short*)(ws + 18874368);
    short* vbt   = (short*)(ws + 23592960);
    short* wts   = (short*)(ws + 33030144);         // 14.16 MB/layer (x6 if allw)

    const long long WL = 7077888;
    bool allw = ws_size >= 117964800ull;            // 33030144 + 6*14155776
    size_t cntOff = allw ? 117964800ull : 47185920ull;
    bool fuseLN = ws_size >= cntOff + 256;
    int* cnt = fuseLN ? (int*)(ws + cntOff) : nullptr;

    embed_ln0_k<<<dim3(2 * T3), 256, 0, stream>>>(states, actions, goals, timesteps,
        W_s, b_s, W_a, b_a, W_g, b_g, E_t, ln0_g, ln0_b, x_f, x_bf);

    if (allw)
        conv64_k<<<dim3(1728 * NL / 2), 256, 0, stream>>>(Wq, Wk, Wv, Wp, W1, W2, wts, 0);

    for (int l = 0; l < NL; ++l) {
        size_t bo = (size_t)l * CDIM, b1o = (size_t)l * 4 * CDIM;
        if (!allw)
            conv64_k<<<dim3(1728 / 2), 256, 0, stream>>>(Wq, Wk, Wv, Wp, W1, W2, wts, l);
        short* wb  = wts + (allw ? (long long)l * WL : 0);
        short* Wqt = wb;
        short* Wkt = wb + 589824;
        short* Wvt = wb + 1179648;
        short* Wpt = wb + 1769472;
        short* W1t = wb + 2359296;
        short* W2t = wb + 4718592;

        gemm6_k<64, 64, 0, 1, 0><<<dim3(12, 48, 3), 256, 0, stream>>>(x_bf, Wqt, Wkt, Wvt,
            bq + bo, bk + bo, bv + bo, nullptr, qb, kb, vbt, CDIM, CDIM,
            nullptr, nullptr, nullptr, nullptr, nullptr);
        attn_k<<<dim3(576), 256, 0, stream>>>(qb, kb, vbt, x_bf, cnt);
        if (fuseLN) {
            gemm6_k<64, 64, 1, 1, 1><<<dim3(12, 48, 1), 256, 0, stream>>>(x_bf, Wpt, nullptr, nullptr,
                bp + bo, nullptr, nullptr, x_f, nullptr, nullptr, nullptr, CDIM, CDIM,
                ln1_g + bo, ln1_b + bo, x_bf, cnt, nullptr);
            gemm6_k<128, 64, 2, 0, 0><<<dim3(48, 24, 1), 256, 0, stream>>>(x_bf, W1t, nullptr, nullptr,
                b1 + b1o, nullptr, nullptr, nullptr, h_bf, nullptr, nullptr, 4 * CDIM, CDIM,
                nullptr, nullptr, nullptr, nullptr, cnt);
            gemm6_k<64, 64, 1, 1, 1><<<dim3(12, 48, 1), 256, 0, stream>>>(h_bf, W2t, nullptr, nullptr,
                b2 + bo, nullptr, nullptr, x_f, nullptr, nullptr, nullptr, CDIM, 4 * CDIM,
                ln2_g + bo, ln2_b + bo, x_bf, cnt, nullptr);
        } else {
            gemm6_k<64, 64, 1, 1, 0><<<dim3(12, 48, 1), 256, 0, stream>>>(x_bf, Wpt, nullptr, nullptr,
                bp + bo, nullptr, nullptr, x_f, nullptr, nullptr, nullptr, CDIM, CDIM,
                nullptr, nullptr, nullptr, nullptr, nullptr);
            ln_k<<<dim3(768), 256, 0, stream>>>(x_f, x_bf, ln1_g + bo, ln1_b + bo);
            gemm6_k<128, 64, 2, 0, 0><<<dim3(48, 24, 1), 256, 0, stream>>>(x_bf, W1t, nullptr, nullptr,
                b1 + b1o, nullptr, nullptr, nullptr, h_bf, nullptr, nullptr, 4 * CDIM, CDIM,
                nullptr, nullptr, nullptr, nullptr, nullptr);
            gemm6_k<64, 64, 1, 1, 0><<<dim3(12, 48, 1), 256, 0, stream>>>(h_bf, W2t, nullptr, nullptr,
                b2 + bo, nullptr, nullptr, x_f, nullptr, nullptr, nullptr, CDIM, 4 * CDIM,
                nullptr, nullptr, nullptr, nullptr, nullptr);
            ln_k<<<dim3(768), 256, 0, stream>>>(x_f, x_bf, ln2_g + bo, ln2_b + bo);
        }
    }

    head_k<<<dim3(1024, 2), 64, 0, stream>>>(x_bf, W_ps, b_ps, W_pa, b_pa, (float*)d_out);
}

// Round 14
// 1069.072 us; speedup vs baseline: 2.0089x; 2.0089x over previous
//
#include <hip/hip_runtime.h>

#define SEQ 512
#define T3 1536
#define CDIM 768
#define NH 12
#define HD 64
#define NL 6

typedef __attribute__((ext_vector_type(8))) short bh8;
typedef __attribute__((ext_vector_type(4))) short s4;
typedef __attribute__((ext_vector_type(4))) float f4;

__device__ inline short f2bf(float f) {
    union { float f; unsigned u; } x; x.f = f;
    unsigned r = x.u + 0x7FFFu + ((x.u >> 16) & 1u);
    return (short)(r >> 16);
}

__device__ inline float bf2f(short s) {
    union { unsigned u; float f; } x;
    x.u = ((unsigned)(unsigned short)s) << 16;
    return x.f;
}

__device__ inline void gload16(const short* g, const short* l) {
    __builtin_amdgcn_global_load_lds(
        (const __attribute__((address_space(1))) unsigned int*)g,
        (__attribute__((address_space(3))) unsigned int*)l, 16, 0, 0);
}

__device__ inline float block_sum(float v, volatile float* red, int tid) {
    #pragma unroll
    for (int off = 32; off > 0; off >>= 1) v += __shfl_down(v, off, 64);
    __syncthreads();
    if ((tid & 63) == 0) red[tid >> 6] = v;
    __syncthreads();
    return red[0] + red[1] + red[2] + red[3];
}

// ---------------- weight transpose + bf16 conversion (r8 best: 71us) -------
__global__ __launch_bounds__(256) void conv64_k(
        const float* __restrict__ Wq, const float* __restrict__ Wk,
        const float* __restrict__ Wv, const float* __restrict__ Wp,
        const float* __restrict__ W1, const float* __restrict__ W2,
        short* __restrict__ dst, int l0) {
    __shared__ float t2[2][64][65];      // [tile][n][k]
    int tid = threadIdx.x;
    int rk = tid >> 4, cn4 = (tid & 15) * 4;
    const float* srcA[2]; short* dA[2]; int KA[2], k0A[2], n0A[2];
    f4 vv[2][4];
    #pragma unroll
    for (int i = 0; i < 2; ++i) {
        int tt = blockIdx.x * 2 + i;
        int lrel = tt / 1728, r = tt - lrel * 1728;
        int l = l0 + lrel;
        short* dstL = dst + (size_t)lrel * 7077888;
        const float* src; short* d; int K, N, tk, tn;
        if (r < 576) {
            int mat = r / 144, t = r - mat * 144;
            tk = t / 12; tn = t % 12; K = 768; N = 768;
            const float* srcs[4] = {Wq, Wk, Wv, Wp};
            src = srcs[mat] + (size_t)l * 589824;
            d = dstL + mat * 589824;
        } else if (r < 1152) {
            int t = r - 576; tk = t / 48; tn = t % 48; K = 768; N = 3072;
            src = W1 + (size_t)l * 2359296; d = dstL + 2359296;
        } else {
            int t = r - 1152; tk = t / 12; tn = t % 12; K = 3072; N = 768;
            src = W2 + (size_t)l * 2359296; d = dstL + 4718592;
        }
        int k0 = tk * 64, n0 = tn * 64;
        srcA[i] = src; dA[i] = d; KA[i] = K; k0A[i] = k0; n0A[i] = n0;
        #pragma unroll
        for (int p = 0; p < 4; ++p)
            vv[i][p] = *(const f4*)(src + (size_t)(k0 + p * 16 + rk) * N + n0 + cn4);
    }
    #pragma unroll
    for (int i = 0; i < 2; ++i)
    #pragma unroll
    for (int p = 0; p < 4; ++p) {
        t2[i][cn4][p * 16 + rk]     = vv[i][p][0];
        t2[i][cn4 + 1][p * 16 + rk] = vv[i][p][1];
        t2[i][cn4 + 2][p * 16 + rk] = vv[i][p][2];
        t2[i][cn4 + 3][p * 16 + rk] = vv[i][p][3];
    }
    __syncthreads();
    int n = tid >> 2, kb = (tid & 3) * 16;
    #pragma unroll
    for (int i = 0; i < 2; ++i) {
        f4 a0 = *(const f4*)&t2[i][n][kb];
        f4 a1 = *(const f4*)&t2[i][n][kb + 4];
        f4 a2 = *(const f4*)&t2[i][n][kb + 8];
        f4 a3 = *(const f4*)&t2[i][n][kb + 12];
        bh8 o0, o1;
        o0[0] = f2bf(a0[0]); o0[1] = f2bf(a0[1]); o0[2] = f2bf(a0[2]); o0[3] = f2bf(a0[3]);
        o0[4] = f2bf(a1[0]); o0[5] = f2bf(a1[1]); o0[6] = f2bf(a1[2]); o0[7] = f2bf(a1[3]);
        o1[0] = f2bf(a2[0]); o1[1] = f2bf(a2[1]); o1[2] = f2bf(a2[2]); o1[3] = f2bf(a2[3]);
        o1[4] = f2bf(a3[0]); o1[5] = f2bf(a3[1]); o1[6] = f2bf(a3[2]); o1[7] = f2bf(a3[3]);
        short* wp = dA[i] + (size_t)(n0A[i] + n) * KA[i] + k0A[i] + kb;
        *(bh8*)wp = o0;
        *(bh8*)(wp + 8) = o1;
    }
}

// ---------------- embedding + LN0 ----------------
__global__ __launch_bounds__(256) void embed_ln0_k(
        const float* __restrict__ states, const float* __restrict__ actions,
        const float* __restrict__ goals, const int* __restrict__ timesteps,
        const float* __restrict__ W_s, const float* __restrict__ b_s,
        const float* __restrict__ W_a, const float* __restrict__ b_a,
        const float* __restrict__ W_g, const float* __restrict__ b_g,
        const float* __restrict__ E_t, const float* __restrict__ g0,
        const float* __restrict__ bb0, float* __restrict__ x, short* __restrict__ xb) {
    int row = blockIdx.x;
    int b = row / T3, t3 = row - b * T3;
    int t = t3 / 3, kind = t3 - t * 3;
    __shared__ float inv[64];
    __shared__ float xr[CDIM];
    __shared__ float red[4];
    int tid = threadIdx.x;
    const float* src; const float* W; const float* bias;
    if (kind == 0)      { src = goals + b * 64;                       W = W_g; bias = b_g; }
    else if (kind == 1) { src = states + ((size_t)b * SEQ + t) * 64;  W = W_s; bias = b_s; }
    else                { src = actions + ((size_t)b * SEQ + t) * 64; W = W_a; bias = b_a; }
    if (tid < 64) inv[tid] = src[tid];
    __syncthreads();
    int ts = timesteps[b * SEQ + t];
    for (int c = tid; c < CDIM; c += 256) {
        float acc = bias[c] + E_t[(size_t)ts * CDIM + c];
        #pragma unroll 8
        for (int kk = 0; kk < 64; ++kk) acc += inv[kk] * W[kk * CDIM + c];
        xr[c] = acc;
    }
    __syncthreads();
    float v0 = xr[tid], v1 = xr[tid + 256], v2 = xr[tid + 512];
    float mean = block_sum(v0 + v1 + v2, red, tid) * (1.f / CDIM);
    float d0 = v0 - mean, d1 = v1 - mean, d2 = v2 - mean;
    float var = block_sum(d0 * d0 + d1 * d1 + d2 * d2, red, tid) * (1.f / CDIM);
    float rs = rsqrtf(var + 1e-5f);
    float* w = x + (size_t)row * CDIM;
    short* wb = xb + (size_t)row * CDIM;
    float o0 = d0 * rs * g0[tid]       + bb0[tid];
    float o1 = d1 * rs * g0[tid + 256] + bb0[tid + 256];
    float o2 = d2 * rs * g0[tid + 512] + bb0[tid + 512];
    w[tid] = o0; w[tid + 256] = o1; w[tid + 512] = o2;
    wb[tid] = f2bf(o0); wb[tid + 256] = f2bf(o1); wb[tid + 512] = f2bf(o2);
}

// ------- in-place LayerNorm, wave-per-row (no barriers), 4 rows/block ------
__global__ __launch_bounds__(256) void ln_k(float* __restrict__ x, short* __restrict__ outb,
                                            const float* __restrict__ g, const float* __restrict__ bb) {
    int wave = threadIdx.x >> 6, lane = threadIdx.x & 63;
    int row = blockIdx.x * 4 + wave;
    float* r = x + (size_t)row * CDIM;
    short* wb = outb + (size_t)row * CDIM;
    float v[12];
    float s = 0.f, s2 = 0.f;
    #pragma unroll
    for (int j = 0; j < 12; ++j) {
        v[j] = r[lane + j * 64];
        s += v[j]; s2 += v[j] * v[j];
    }
    #pragma unroll
    for (int off = 32; off > 0; off >>= 1) { s += __shfl_xor(s, off, 64); s2 += __shfl_xor(s2, off, 64); }
    float mean = s * (1.f / CDIM);
    float var = s2 * (1.f / CDIM) - mean * mean;
    float rs = rsqrtf(var + 1e-5f);
    #pragma unroll
    for (int j = 0; j < 12; ++j) {
        int c = lane + j * 64;
        float o = (v[j] - mean) * rs * g[c] + bb[c];
        r[c] = o;
        wb[c] = f2bf(o);
    }
}

// ----- BMxBN MFMA GEMM, BK=64, swizzled LDS, gload staging -----------------
// DB=1: double-buffered LDS + counted vmcnt(4) + raw barriers.
// DB=0: single-buffer + __syncthreads.
// A [M][K] bf16, B [N][K] bf16. EPI 0: QKV scatter (z: 0=Q,1=K,2=V^T)
// EPI 1: outF += acc + bias (in-place residual, f32)
// EPI 2: outQ = bf16(gelu(acc + bias))
template<int BM, int BN, int EPI, int DB>
__global__ __launch_bounds__(256) void gemm6_k(
        const short* __restrict__ A, const short* __restrict__ B0,
        const short* __restrict__ B1, const short* __restrict__ B2,
        const float* __restrict__ bias0, const float* __restrict__ bias1,
        const float* __restrict__ bias2,
        float* __restrict__ outF, short* __restrict__ outQ,
        short* __restrict__ outK, short* __restrict__ outV,
        int N, int K) {
    const short* Bw = B0; const float* bias = bias0; short* outB = outQ;
    int zid = 0;
    if (EPI == 0) {
        zid = blockIdx.z;
        if (zid == 1) { Bw = B1; bias = bias1; outB = outK; }
        else if (zid == 2) { Bw = B2; bias = bias2; outB = outV; }
    }
    __shared__ short As[(DB ? 2 : 1) * BM * 64];
    __shared__ short Bs[(DB ? 2 : 1) * BN * 64];
    int tid = threadIdx.x, lane = tid & 63, wave = tid >> 6;
    int wm = wave >> 1, wn = wave & 1, lr = lane & 15, lg = lane >> 4;
    int bm = blockIdx.y * BM, bn = blockIdx.x * BN;
    int rl = lane >> 3, ch = (lane & 7) ^ rl;
    constexpr int MI = BM / 32, NI = BN / 32;
    f4 acc[MI][NI] = {};

    auto STAGE = [&](int k0, int buf) {
        #pragma unroll
        for (int j = 0; j < BM / 32; ++j)
            gload16(A + (size_t)(bm + wave * (BM / 4) + j * 8 + rl) * K + k0 + ch * 8,
                    As + buf * BM * 64 + (wave * (BM / 4) + j * 8) * 64);
        #pragma unroll
        for (int j = 0; j < BN / 32; ++j)
            gload16(Bw + (size_t)(bn + wave * (BN / 4) + j * 8 + rl) * K + k0 + ch * 8,
                    Bs + buf * BN * 64 + (wave * (BN / 4) + j * 8) * 64);
    };

    auto COMPUTE = [&](int buf) {
        bh8 af[MI][2], bf[NI][2];
        #pragma unroll
        for (int mi = 0; mi < MI; ++mi)
        #pragma unroll
        for (int kk = 0; kk < 2; ++kk) {
            int m = wm * (BM / 2) + mi * 16 + lr;
            af[mi][kk] = *(const bh8*)(As + buf * BM * 64 + m * 64 + (((kk * 4 + lg) ^ (lr & 7)) * 8));
        }
        #pragma unroll
        for (int ni = 0; ni < NI; ++ni)
        #pragma unroll
        for (int kk = 0; kk < 2; ++kk) {
            int n = wn * (BN / 2) + ni * 16 + lr;
            bf[ni][kk] = *(const bh8*)(Bs + buf * BN * 64 + n * 64 + (((kk * 4 + lg) ^ (lr & 7)) * 8));
        }
        #pragma unroll
        for (int kk = 0; kk < 2; ++kk)
        #pragma unroll
        for (int mi = 0; mi < MI; ++mi)
        #pragma unroll
        for (int ni = 0; ni < NI; ++ni)
            acc[mi][ni] = __builtin_amdgcn_mfma_f32_16x16x32_bf16(af[mi][kk], bf[ni][kk], acc[mi][ni], 0, 0, 0);
    };

    if (DB) {
        STAGE(0, 0);
        int cur = 0;
        for (int k0 = 0; k0 < K; k0 += 64) {
            if (k0 + 64 < K) {
                STAGE(k0 + 64, cur ^ 1);
                asm volatile("s_waitcnt vmcnt(4)" ::: "memory");
            } else {
                asm volatile("s_waitcnt vmcnt(0)" ::: "memory");
            }
            __builtin_amdgcn_s_barrier();
            __builtin_amdgcn_sched_barrier(0);
            COMPUTE(cur);
            __builtin_amdgcn_sched_barrier(0);
            __builtin_amdgcn_s_barrier();
            cur ^= 1;
        }
    } else {
        for (int k0 = 0; k0 < K; k0 += 64) {
            STAGE(k0, 0);
            __syncthreads();
            COMPUTE(0);
            __syncthreads();
        }
    }

    #pragma unroll
    for (int mi = 0; mi < MI; ++mi)
    #pragma unroll
    for (int ni = 0; ni < NI; ++ni)
    #pragma unroll
    for (int i = 0; i < 4; ++i) {
        int row = bm + wm * (BM / 2) + mi * 16 + lg * 4 + i;
        int col = bn + wn * (BN / 2) + ni * 16 + lr;
        float vv = acc[mi][ni][i] + bias[col];
        if (EPI == 0) {
            int b = row / T3, t = row - b * T3;
            int h = col >> 6, d = col & 63;
            if (zid == 2) outB[((size_t)(b * NH + h) * 64 + d) * T3 + t] = f2bf(vv);
            else          outB[((((size_t)b * NH + h) * T3 + t) << 6) + d] = f2bf(vv);
        } else if (EPI == 1) {
            size_t idx = (size_t)row * N + col;
            outF[idx] = vv + outF[idx];
        } else {
            float gl = 0.5f * vv * (1.0f + erff(vv * 0.70710678118f));
            outQ[(size_t)row * N + col] = f2bf(gl);
        }
    }
}

// ---------------- causal flash attention (no-max softmax, dbuf gload) -------
// q,k: [bh][T3][64] bf16 ; vt: [bh][64][T3] bf16 (pre-transposed by QKV gemm)
__global__ __launch_bounds__(256) void attn_k(const short* __restrict__ q, const short* __restrict__ k,
                                              const short* __restrict__ vt, short* __restrict__ att) {
    int idx = blockIdx.x;
    int qt = 23 - (idx / 24);          // heavy-first ordering
    int bh = idx % 24;
    int b = bh / NH, h = bh - b * NH;
    const short* qb = q  + (size_t)bh * T3 * HD;
    const short* kb = k  + (size_t)bh * T3 * HD;
    const short* vb = vt + (size_t)bh * HD * T3;
    __shared__ short Ks[2][4096];
    __shared__ short Vs[2][4096];
    __shared__ short Pl[4][16][72];
    int tid = threadIdx.x, lane = tid & 63, wave = tid >> 6;
    int lr = lane & 15, lg = lane >> 4;
    int rl = lane >> 3, ch = (lane & 7) ^ rl;
    int qrow0 = qt * 64 + wave * 16;
    bh8 aq0 = *(const bh8*)(qb + (size_t)(qrow0 + lr) * HD + lg * 8);
    bh8 aq1 = *(const bh8*)(qb + (size_t)(qrow0 + lr) * HD + 32 + lg * 8);
    f4 o[4] = {};
    float lsum[4] = {0.f, 0.f, 0.f, 0.f};

    auto STAGE = [&](int kt2, int buf) {
        const short* kb2 = kb + (size_t)kt2 * 64 * HD;
        #pragma unroll
        for (int j = 0; j < 2; ++j)
            gload16(kb2 + (wave * 16 + j * 8 + rl) * HD + ch * 8,
                    &Ks[buf][(wave * 16 + j * 8) * 64]);
        const short* vb2 = vb + kt2 * 64;
        #pragma unroll
        for (int j = 0; j < 2; ++j)
            gload16(vb2 + (size_t)(wave * 16 + j * 8 + rl) * T3 + ch * 8,
                    &Vs[buf][(wave * 16 + j * 8) * 64]);
    };

    STAGE(0, 0);
    int cur = 0;
    for (int kt = 0; kt <= qt; ++kt) {
        if (kt < qt) {
            STAGE(kt + 1, cur ^ 1);
            asm volatile("s_waitcnt vmcnt(4)" ::: "memory");
        } else {
            asm volatile("s_waitcnt vmcnt(0)" ::: "memory");
        }
        __builtin_amdgcn_s_barrier();
        __builtin_amdgcn_sched_barrier(0);
        const short* Kb = &Ks[cur][0];
        const short* Vb = &Vs[cur][0];
        f4 s[4];
        #pragma unroll
        for (int nf = 0; nf < 4; ++nf) {
            int tok = nf * 16 + lr;
            bh8 bk0 = *(const bh8*)(Kb + tok * 64 + ((lg ^ (lr & 7)) * 8));
            bh8 bk1 = *(const bh8*)(Kb + tok * 64 + (((4 + lg) ^ (lr & 7)) * 8));
            f4 t = {};
            t = __builtin_amdgcn_mfma_f32_16x16x32_bf16(aq0, bk0, t, 0, 0, 0);
            t = __builtin_amdgcn_mfma_f32_16x16x32_bf16(aq1, bk1, t, 0, 0, 0);
            s[nf] = t;
        }
        #pragma unroll
        for (int nf = 0; nf < 4; ++nf)
        #pragma unroll
        for (int i = 0; i < 4; ++i) {
            float p = __expf(s[nf][i] * 0.125f);
            if (kt == qt && (nf * 16 + lr) > (wave * 16 + lg * 4 + i)) p = 0.f;
            lsum[i] += p;
            Pl[wave][lg * 4 + i][nf * 16 + lr] = f2bf(p);
        }
        bh8 ap0 = *(const bh8*)&Pl[wave][lr][lg * 8];
        bh8 ap1 = *(const bh8*)&Pl[wave][lr][32 + lg * 8];
        #pragma unroll
        for (int nf = 0; nf < 4; ++nf) {
            int d = nf * 16 + lr;
            bh8 bv0 = *(const bh8*)(Vb + d * 64 + ((lg ^ (lr & 7)) * 8));
            bh8 bv1 = *(const bh8*)(Vb + d * 64 + (((4 + lg) ^ (lr & 7)) * 8));
            o[nf] = __builtin_amdgcn_mfma_f32_16x16x32_bf16(ap0, bv0, o[nf], 0, 0, 0);
            o[nf] = __builtin_amdgcn_mfma_f32_16x16x32_bf16(ap1, bv1, o[nf], 0, 0, 0);
        }
        __builtin_amdgcn_sched_barrier(0);
        __builtin_amdgcn_s_barrier();
        cur ^= 1;
    }
    float linv[4];
    #pragma unroll
    for (int i = 0; i < 4; ++i) {
        float l = lsum[i];
        #pragma unroll
        for (int off = 1; off < 16; off <<= 1) l += __shfl_xor(l, off, 16);
        linv[i] = 1.f / l;
    }
    #pragma unroll
    for (int nf = 0; nf < 4; ++nf)
    #pragma unroll
    for (int i = 0; i < 4; ++i) {
        int qrow = qrow0 + lg * 4 + i;
        att[((size_t)b * T3 + qrow) * CDIM + h * 64 + nf * 16 + lr] = f2bf(o[nf][i] * linv[i]);
    }
}

// ---------------- output heads (bf16 activations) ----------------
__global__ __launch_bounds__(64) void head_k(const short* __restrict__ x,
                                             const float* __restrict__ Wps, const float* __restrict__ bps,
                                             const float* __restrict__ Wpa, const float* __restrict__ bpa,
                                             float* __restrict__ out) {
    int o = blockIdx.y;
    int bs = blockIdx.x;
    int b = bs >> 9, t = bs & 511;
    int kind = (o == 0) ? 2 : 1;
    const float* W = (o == 0) ? Wps : Wpa;
    const float* bi = (o == 0) ? bps : bpa;
    const short* xr = x + ((size_t)b * T3 + t * 3 + kind) * CDIM;
    int n = threadIdx.x;
    float a0 = 0.f, a1 = 0.f, a2 = 0.f, a3 = 0.f;
    for (int kk = 0; kk < CDIM; kk += 4) {
        s4 xv = *(const s4*)(xr + kk);
        a0 = fmaf(bf2f(xv[0]), W[(kk)     * 64 + n], a0);
        a1 = fmaf(bf2f(xv[1]), W[(kk + 1) * 64 + n], a1);
        a2 = fmaf(bf2f(xv[2]), W[(kk + 2) * 64 + n], a2);
        a3 = fmaf(bf2f(xv[3]), W[(kk + 3) * 64 + n], a3);
    }
    float acc = bi[n] + ((a0 + a1) + (a2 + a3));
    if (o == 1) acc = tanhf(acc);
    out[(((size_t)o * 2 + b) * SEQ + t) * 64 + n] = acc;
}

extern "C" void kernel_launch(void* const* d_in, const int* in_sizes, int n_in,
                              void* d_out, int out_size, void* d_ws, size_t ws_size,
                              hipStream_t stream) {
    const float* states    = (const float*)d_in[0];
    const float* actions   = (const float*)d_in[1];
    const float* goals     = (const float*)d_in[2];
    const int*   timesteps = (const int*)d_in[4];
    const float* W_s = (const float*)d_in[5];  const float* b_s = (const float*)d_in[6];
    const float* W_a = (const float*)d_in[7];  const float* b_a = (const float*)d_in[8];
    const float* W_g = (const float*)d_in[9];  const float* b_g = (const float*)d_in[10];
    const float* E_t = (const float*)d_in[11];
    const float* ln0_g = (const float*)d_in[12]; const float* ln0_b = (const float*)d_in[13];
    const float* Wq = (const float*)d_in[14]; const float* bq = (const float*)d_in[15];
    const float* Wk = (const float*)d_in[16]; const float* bk = (const float*)d_in[17];
    const float* Wv = (const float*)d_in[18]; const float* bv = (const float*)d_in[19];
    const float* Wp = (const float*)d_in[20]; const float* bp = (const float*)d_in[21];
    const float* ln1_g = (const float*)d_in[22]; const float* ln1_b = (const float*)d_in[23];
    const float* W1 = (const float*)d_in[24]; const float* b1 = (const float*)d_in[25];
    const float* W2 = (const float*)d_in[26]; const float* b2 = (const float*)d_in[27];
    const float* ln2_g = (const float*)d_in[28]; const float* ln2_b = (const float*)d_in[29];
    const float* W_ps = (const float*)d_in[30]; const float* b_ps = (const float*)d_in[31];
    const float* W_pa = (const float*)d_in[32]; const float* b_pa = (const float*)d_in[33];

    char* ws = (char*)d_ws;
    float* x_f   = (float*)(ws);                    //  9.44 MB [3072][768] f32 residual
    short* x_bf  = (short*)(ws + 9437184);          //  4.72 MB [3072][768] bf16 (LN out / attn out)
    // U region (18.87 MB): h_bf  OR  (qb,kb,vbt) -- never live simultaneously
    short* h_bf  = (short*)(ws + 14155776);         // 18.87 MB [3072][3072] bf16
    short* qb    = (short*)(ws + 14155776);         //  4.72 MB [B,H,T3,D] bf16
    short* kb    = (short*)(ws + 18874368);         //  4.72 MB [B,H,T3,D]
    short* vbt   = (short*)(ws + 23592960);         //  4.72 MB [B,H,D,T3]
    short* wts   = (short*)(ws + 33030144);         // 14.16 MB/layer (x6 if allw)

    const long long WL = 7077888;
    bool allw = ws_size >= 117964800ull;            // 33030144 + 6*14155776

    embed_ln0_k<<<dim3(2 * T3), 256, 0, stream>>>(states, actions, goals, timesteps,
        W_s, b_s, W_a, b_a, W_g, b_g, E_t, ln0_g, ln0_b, x_f, x_bf);

    if (allw)
        conv64_k<<<dim3(1728 * NL / 2), 256, 0, stream>>>(Wq, Wk, Wv, Wp, W1, W2, wts, 0);

    for (int l = 0; l < NL; ++l) {
        size_t bo = (size_t)l * CDIM, b1o = (size_t)l * 4 * CDIM;
        if (!allw)
            conv64_k<<<dim3(1728 / 2), 256, 0, stream>>>(Wq, Wk, Wv, Wp, W1, W2, wts, l);
        short* wb  = wts + (allw ? (long long)l * WL : 0);
        short* Wqt = wb;
        short* Wkt = wb + 589824;
        short* Wvt = wb + 1179648;
        short* Wpt = wb + 1769472;
        short* W1t = wb + 2359296;
        short* W2t = wb + 4718592;

        gemm6_k<64, 64, 0, 1><<<dim3(12, 48, 3), 256, 0, stream>>>(x_bf, Wqt, Wkt, Wvt,
            bq + bo, bk + bo, bv + bo, nullptr, qb, kb, vbt, CDIM, CDIM);
        attn_k<<<dim3(576), 256, 0, stream>>>(qb, kb, vbt, x_bf);
        gemm6_k<64, 64, 1, 1><<<dim3(12, 48, 1), 256, 0, stream>>>(x_bf, Wpt, nullptr, nullptr,
            bp + bo, nullptr, nullptr, x_f, nullptr, nullptr, nullptr, CDIM, CDIM);
        ln_k<<<dim3(768), 256, 0, stream>>>(x_f, x_bf, ln1_g + bo, ln1_b + bo);
        gemm6_k<128, 64, 2, 0><<<dim3(48, 24, 1), 256, 0, stream>>>(x_bf, W1t, nullptr, nullptr,
            b1 + b1o, nullptr, nullptr, nullptr, h_bf, nullptr, nullptr, 4 * CDIM, CDIM);
        gemm6_k<64, 64, 1, 1><<<dim3(12, 48, 1), 256, 0, stream>>>(h_bf, W2t, nullptr, nullptr,
            b2 + bo, nullptr, nullptr, x_f, nullptr, nullptr, nullptr, CDIM, 4 * CDIM);
        ln_k<<<dim3(768), 256, 0, stream>>>(x_f, x_bf, ln2_g + bo, ln2_b + bo);
    }

    head_k<<<dim3(1024, 2), 64, 0, stream>>>(x_bf, W_ps, b_ps, W_pa, b_pa, (float*)d_out);
}